// Round 1
// baseline (302.226 us; speedup 1.0000x reference)
//
#include <hip/hip_runtime.h>
#include <hip/hip_bf16.h>
#include <math.h>

#define DEVI __device__ __forceinline__

typedef __bf16 bf16;
typedef bf16 bf16x4 __attribute__((ext_vector_type(4)));
typedef bf16 bf16x8 __attribute__((ext_vector_type(8)));
typedef float f32x4 __attribute__((ext_vector_type(4)));

// ---- problem dims (fixed) ----
constexpr int Bb = 2, Hh = 32, Ww = 32, Dd = 32;
constexpr int Nn = Hh * Ww * Dd;      // 32768
constexpr int BN = Bb * Nn;           // 65536 tokens
constexpr int CIN = 160, CHH = 640;

// ---- workspace layout (bytes, all 256-aligned) ----
constexpr size_t XB_OFF = 0;                                  // x as bf16: BN*CIN*2 = 20,971,520
constexpr size_t W1_OFF = XB_OFF + (size_t)BN * CIN * 2;      // fc1_w bf16: 204,800
constexpr size_t W2_OFF = W1_OFF + (size_t)CHH * CIN * 2;     // fc2_w bf16: 204,800
constexpr size_t WT_OFF = W2_OFF + (size_t)CIN * CHH * 2;     // dw_w transposed f32 [27][640]: 69,120
constexpr size_t ZP_OFF = WT_OFF + (size_t)27 * CHH * 4;      // zero page: 8192
constexpr size_t H1_OFF = ZP_OFF + 8192;                      // h1 bf16: 83,886,080
constexpr size_t H2_OFF = H1_OFF + (size_t)BN * CHH * 2;      // h2 bf16: 83,886,080

DEVI void async16(const void* g, void* l) {
  __builtin_amdgcn_global_load_lds(
      (const __attribute__((address_space(1))) void*)g,
      (__attribute__((address_space(3))) void*)l, 16, 0, 0);
}

// ---- prep: x -> bf16 ----
__global__ __launch_bounds__(256) void k_prep_x(const float* __restrict__ x,
                                                bf16* __restrict__ xb, int n4) {
  int i = blockIdx.x * 256 + threadIdx.x;
  if (i >= n4) return;
  float4 v = reinterpret_cast<const float4*>(x)[i];
  bf16x4 o;
  o[0] = (bf16)v.x; o[1] = (bf16)v.y; o[2] = (bf16)v.z; o[3] = (bf16)v.w;
  reinterpret_cast<bf16x4*>(xb)[i] = o;
}

// ---- prep: weights -> bf16, dw_w transpose, zero page ----
__global__ __launch_bounds__(256) void k_prep_w(const float* __restrict__ fc1w,
                                                const float* __restrict__ fc2w,
                                                const float* __restrict__ dww,
                                                bf16* __restrict__ w1b,
                                                bf16* __restrict__ w2b,
                                                float* __restrict__ wT,
                                                unsigned* __restrict__ zp) {
  int i = blockIdx.x * 256 + threadIdx.x;
  const int NW = CHH * CIN;  // 102400
  if (i < NW) {
    w1b[i] = (bf16)fc1w[i];
  } else if (i < 2 * NW) {
    int j = i - NW;
    w2b[j] = (bf16)fc2w[j];
  } else if (i < 2 * NW + 27 * CHH) {
    int j = i - 2 * NW;
    int ch = j / 27, tap = j % 27;
    wT[tap * CHH + ch] = dww[j];
  } else if (i < 2 * NW + 27 * CHH + 2048) {
    zp[i - (2 * NW + 27 * CHH)] = 0u;
  }
}

// ---- GEMM1: h1[t,ch] = sum_c xs[t,c] * fc1_w[ch,c] + fc1_b[ch], shift(H) fused ----
// tile 128(M) x 128(N), BK=32, K=160 (5 steps). 4 waves, each 64x64 (4x4 frags).
__global__ __launch_bounds__(256) void k_gemm1(const bf16* __restrict__ xb,
                                               const bf16* __restrict__ w1b,
                                               const float* __restrict__ fc1b,
                                               const bf16* __restrict__ zp,
                                               bf16* __restrict__ h1b) {
  __shared__ bf16 lsA[128 * 32];  // 8KB
  __shared__ bf16 lsB[128 * 32];  // 8KB
  const int tid = threadIdx.x;
  const int lane = tid & 63, wave = tid >> 6;
  const int row0 = blockIdx.x * 128;   // token base
  const int col0 = blockIdx.y * 128;   // channel base

  f32x4 acc[4][4] = {};
  const int wr = wave >> 1, wc = wave & 1;
  const int rl = lane & 15, kb = (lane >> 4) * 8;

  for (int ks = 0; ks < 5; ++ks) {
    __syncthreads();
    const int s = ks - 2;  // shift for channel chunk ks (32 channels each)
    // stage A (128x32): chunk c = issue*256+tid -> row=c>>2, kcol=(c&3)*8
#pragma unroll
    for (int issue = 0; issue < 2; ++issue) {
      int c = issue * 256 + tid;
      int ar = c >> 2;
      int kc = (c & 3) * 8;
      int t = row0 + ar;
      int h = (t >> 10) & 31;
      int hs = h - s;
      const bf16* src;
      if (hs >= 0 && hs < 32)
        src = xb + (size_t)(t - s * 1024) * CIN + ks * 32 + kc;
      else
        src = zp + (size_t)(c & 63) * 8;
      async16(src, (char*)lsA + issue * 4096 + wave * 1024);
    }
    // stage B (128x32) from w1b rows col0+row
#pragma unroll
    for (int issue = 0; issue < 2; ++issue) {
      int c = issue * 256 + tid;
      int br = c >> 2;
      int kc = (c & 3) * 8;
      const bf16* src = w1b + (size_t)(col0 + br) * CIN + ks * 32 + kc;
      async16(src, (char*)lsB + issue * 4096 + wave * 1024);
    }
    __syncthreads();
    bf16x8 af[4], bfr[4];
#pragma unroll
    for (int mi = 0; mi < 4; ++mi)
      af[mi] = *(const bf16x8*)&lsA[(wr * 64 + mi * 16 + rl) * 32 + kb];
#pragma unroll
    for (int ni = 0; ni < 4; ++ni)
      bfr[ni] = *(const bf16x8*)&lsB[(wc * 64 + ni * 16 + rl) * 32 + kb];
#pragma unroll
    for (int mi = 0; mi < 4; ++mi)
#pragma unroll
      for (int ni = 0; ni < 4; ++ni)
        acc[mi][ni] = __builtin_amdgcn_mfma_f32_16x16x32_bf16(af[mi], bfr[ni], acc[mi][ni], 0, 0, 0);
  }
  // C write: row=(lane>>4)*4+r, col=lane&15  [m89-verified layout]
  const int rq = lane >> 4;
#pragma unroll
  for (int mi = 0; mi < 4; ++mi) {
#pragma unroll
    for (int ni = 0; ni < 4; ++ni) {
      int col = col0 + wc * 64 + ni * 16 + rl;
      float bias = fc1b[col];
#pragma unroll
      for (int r = 0; r < 4; ++r) {
        int row = row0 + wr * 64 + mi * 16 + rq * 4 + r;
        h1b[(size_t)row * CHH + col] = (bf16)(acc[mi][ni][r] + bias);
      }
    }
  }
}

// ---- depthwise 3x3x3 conv + bias + exact GELU ----
// thread = (token, 8-channel chunk). h1b/h2b layout [t][640].
__global__ __launch_bounds__(256) void k_conv(const bf16* __restrict__ h1b,
                                              const float* __restrict__ wT,
                                              const float* __restrict__ dwb,
                                              bf16* __restrict__ h2b) {
  int g = blockIdx.x * 256 + threadIdx.x;  // < BN*80
  int t = g / 80;
  int c8 = g % 80;
  int ch0 = c8 * 8;
  int n = t & (Nn - 1);
  int h = n >> 10, w = (n >> 5) & 31, d = n & 31;
  float acc[8];
#pragma unroll
  for (int j = 0; j < 8; ++j) acc[j] = dwb[ch0 + j];
#pragma unroll
  for (int kz = 0; kz < 3; ++kz) {
    int hz = h + kz - 1;
    if ((unsigned)hz >= 32u) continue;
#pragma unroll
    for (int ky = 0; ky < 3; ++ky) {
      int wy = w + ky - 1;
      if ((unsigned)wy >= 32u) continue;
#pragma unroll
      for (int kx = 0; kx < 3; ++kx) {
        int dx = d + kx - 1;
        if ((unsigned)dx >= 32u) continue;
        int ts = t + (kz - 1) * 1024 + (ky - 1) * 32 + (kx - 1);
        bf16x8 v = *(const bf16x8*)&h1b[(size_t)ts * CHH + ch0];
        int tap = kz * 9 + ky * 3 + kx;
        const float4 wa = *(const float4*)&wT[tap * CHH + ch0];
        const float4 wb = *(const float4*)&wT[tap * CHH + ch0 + 4];
        acc[0] += (float)v[0] * wa.x; acc[1] += (float)v[1] * wa.y;
        acc[2] += (float)v[2] * wa.z; acc[3] += (float)v[3] * wa.w;
        acc[4] += (float)v[4] * wb.x; acc[5] += (float)v[5] * wb.y;
        acc[6] += (float)v[6] * wb.z; acc[7] += (float)v[7] * wb.w;
      }
    }
  }
  bf16x8 o;
#pragma unroll
  for (int j = 0; j < 8; ++j) {
    float xv = acc[j];
    float gel = 0.5f * xv * (1.0f + erff(xv * 0.70710678118654752f));
    o[j] = (bf16)gel;
  }
  *(bf16x8*)&h2b[(size_t)t * CHH + ch0] = o;
}

// ---- GEMM2: out[t,o] = sum_ch hs[t,ch] * fc2_w[o,ch] + fc2_b[o], shift(W) fused ----
// tile 128(M) x 160(N full), BK=64, K=640 (10 steps). 4 waves, each 32x160 (2x10 frags).
__global__ __launch_bounds__(256) void k_gemm2(const bf16* __restrict__ h2b,
                                               const bf16* __restrict__ w2b,
                                               const float* __restrict__ fc2b,
                                               const bf16* __restrict__ zp,
                                               float* __restrict__ out) {
  __shared__ bf16 lsA[128 * 64];  // 16KB
  __shared__ bf16 lsB[160 * 64];  // 20KB
  const int tid = threadIdx.x, lane = tid & 63, wave = tid >> 6;
  const int row0 = blockIdx.x * 128;
  const int rl = lane & 15, kb = (lane >> 4) * 8;

  f32x4 acc[2][10] = {};

  for (int kt = 0; kt < 10; ++kt) {
    __syncthreads();
    const int k0 = kt * 64;
    const int s = (k0 >> 7) - 2;  // shift for 128-channel chunk; uniform per 64-K slice
    // stage A (128x64): 1024 chunks = 4 issues; c -> row=c>>3, kcol=(c&7)*8
#pragma unroll
    for (int issue = 0; issue < 4; ++issue) {
      int c = issue * 256 + tid;
      int ar = c >> 3;
      int kc = (c & 7) * 8;
      int t = row0 + ar;
      int w = (t >> 5) & 31;
      int wsv = w - s;
      const bf16* src;
      if (wsv >= 0 && wsv < 32)
        src = h2b + (size_t)(t - s * 32) * CHH + k0 + kc;
      else
        src = zp + (size_t)(c & 63) * 8;
      async16(src, (char*)lsA + issue * 4096 + wave * 1024);
    }
    // stage B (160x64): 1280 chunks = 5 issues
#pragma unroll
    for (int issue = 0; issue < 5; ++issue) {
      int c = issue * 256 + tid;
      int br = c >> 3;
      int kc = (c & 7) * 8;
      const bf16* src = w2b + (size_t)br * CHH + k0 + kc;
      async16(src, (char*)lsB + issue * 4096 + wave * 1024);
    }
    __syncthreads();
#pragma unroll
    for (int kk = 0; kk < 2; ++kk) {
      bf16x8 af[2], bfr[10];
#pragma unroll
      for (int mi = 0; mi < 2; ++mi)
        af[mi] = *(const bf16x8*)&lsA[(wave * 32 + mi * 16 + rl) * 64 + kk * 32 + kb];
#pragma unroll
      for (int ni = 0; ni < 10; ++ni)
        bfr[ni] = *(const bf16x8*)&lsB[(ni * 16 + rl) * 64 + kk * 32 + kb];
#pragma unroll
      for (int mi = 0; mi < 2; ++mi)
#pragma unroll
        for (int ni = 0; ni < 10; ++ni)
          acc[mi][ni] = __builtin_amdgcn_mfma_f32_16x16x32_bf16(af[mi], bfr[ni], acc[mi][ni], 0, 0, 0);
    }
  }
  const int rq = lane >> 4;
#pragma unroll
  for (int mi = 0; mi < 2; ++mi) {
#pragma unroll
    for (int ni = 0; ni < 10; ++ni) {
      int col = ni * 16 + rl;
      float bias = fc2b[col];
#pragma unroll
      for (int r = 0; r < 4; ++r) {
        int row = row0 + wave * 32 + mi * 16 + rq * 4 + r;
        out[(size_t)row * CIN + col] = acc[mi][ni][r] + bias;
      }
    }
  }
}

extern "C" void kernel_launch(void* const* d_in, const int* in_sizes, int n_in,
                              void* d_out, int out_size, void* d_ws, size_t ws_size,
                              hipStream_t stream) {
  const float* x    = (const float*)d_in[0];
  const float* fc1w = (const float*)d_in[1];
  const float* fc1b = (const float*)d_in[2];
  const float* dww  = (const float*)d_in[3];
  const float* dwb  = (const float*)d_in[4];
  const float* fc2w = (const float*)d_in[5];
  const float* fc2b = (const float*)d_in[6];
  // d_in[7..9] = H, W, D (compile-time constants here)

  char* ws = (char*)d_ws;
  bf16* xb   = (bf16*)(ws + XB_OFF);
  bf16* w1b  = (bf16*)(ws + W1_OFF);
  bf16* w2b  = (bf16*)(ws + W2_OFF);
  float* wT  = (float*)(ws + WT_OFF);
  bf16* zp   = (bf16*)(ws + ZP_OFF);
  bf16* h1b  = (bf16*)(ws + H1_OFF);
  bf16* h2b  = (bf16*)(ws + H2_OFF);
  float* out = (float*)d_out;

  k_prep_x<<<(BN * CIN / 4) / 256, 256, 0, stream>>>(x, xb, BN * CIN / 4);
  k_prep_w<<<876, 256, 0, stream>>>(fc1w, fc2w, dww, w1b, w2b, wT, (unsigned*)zp);
  dim3 g1(512, 5);
  k_gemm1<<<g1, 256, 0, stream>>>(xb, w1b, fc1b, zp, h1b);
  k_conv<<<(BN * 80) / 256, 256, 0, stream>>>(h1b, wT, dwb, h2b);
  k_gemm2<<<512, 256, 0, stream>>>(h2b, w2b, fc2b, zp, out);
}

// Round 2
// 206.343 us; speedup vs baseline: 1.4647x; 1.4647x over previous
//
#include <hip/hip_runtime.h>
#include <hip/hip_bf16.h>
#include <math.h>

#define DEVI __device__ __forceinline__

typedef __bf16 bf16;
typedef bf16 bf16x4 __attribute__((ext_vector_type(4)));
typedef bf16 bf16x8 __attribute__((ext_vector_type(8)));
typedef float f32x4 __attribute__((ext_vector_type(4)));

// ---- problem dims (fixed) ----
constexpr int Bb = 2, Hh = 32, Ww = 32, Dd = 32;
constexpr int Nn = Hh * Ww * Dd;      // 32768
constexpr int BN = Bb * Nn;           // 65536 tokens
constexpr int CIN = 160, CHH = 640;

// ---- workspace layout (bytes, all 256-aligned) ----
constexpr size_t XB_OFF = 0;                                  // x as bf16: BN*CIN*2 = 20,971,520
constexpr size_t W1_OFF = XB_OFF + (size_t)BN * CIN * 2;      // fc1_w bf16: 204,800
constexpr size_t W2_OFF = W1_OFF + (size_t)CHH * CIN * 2;     // fc2_w bf16: 204,800
constexpr size_t WT_OFF = W2_OFF + (size_t)CIN * CHH * 2;     // dw_w transposed f32 [27][640]: 69,120
constexpr size_t ZP_OFF = WT_OFF + (size_t)27 * CHH * 4;      // zero page: 8192
constexpr size_t H1_OFF = ZP_OFF + 8192;                      // h1 bf16: 83,886,080
constexpr size_t H2_OFF = H1_OFF + (size_t)BN * CHH * 2;      // h2 bf16: 83,886,080

DEVI void async16(const void* g, void* l) {
  __builtin_amdgcn_global_load_lds(
      (const __attribute__((address_space(1))) void*)g,
      (__attribute__((address_space(3))) void*)l, 16, 0, 0);
}

// ---- prep: x -> bf16 ----
__global__ __launch_bounds__(256) void k_prep_x(const float* __restrict__ x,
                                                bf16* __restrict__ xb, int n4) {
  int i = blockIdx.x * 256 + threadIdx.x;
  if (i >= n4) return;
  float4 v = reinterpret_cast<const float4*>(x)[i];
  bf16x4 o;
  o[0] = (bf16)v.x; o[1] = (bf16)v.y; o[2] = (bf16)v.z; o[3] = (bf16)v.w;
  reinterpret_cast<bf16x4*>(xb)[i] = o;
}

// ---- prep: weights -> bf16, dw_w transpose, zero page ----
__global__ __launch_bounds__(256) void k_prep_w(const float* __restrict__ fc1w,
                                                const float* __restrict__ fc2w,
                                                const float* __restrict__ dww,
                                                bf16* __restrict__ w1b,
                                                bf16* __restrict__ w2b,
                                                float* __restrict__ wT,
                                                unsigned* __restrict__ zp) {
  int i = blockIdx.x * 256 + threadIdx.x;
  const int NW = CHH * CIN;  // 102400
  if (i < NW) {
    w1b[i] = (bf16)fc1w[i];
  } else if (i < 2 * NW) {
    int j = i - NW;
    w2b[j] = (bf16)fc2w[j];
  } else if (i < 2 * NW + 27 * CHH) {
    int j = i - 2 * NW;
    int ch = j / 27, tap = j % 27;
    wT[tap * CHH + ch] = dww[j];
  } else if (i < 2 * NW + 27 * CHH + 2048) {
    zp[i - (2 * NW + 27 * CHH)] = 0u;
  }
}

// ---- GEMM1: h1[t,ch] = sum_c xs[t,c] * fc1_w[ch,c] + fc1_b[ch], shift(H) fused ----
// tile 128(M) x 128(N), BK=32, K=160 (5 steps). 4 waves, each 64x64 (4x4 frags).
__global__ __launch_bounds__(256) void k_gemm1(const bf16* __restrict__ xb,
                                               const bf16* __restrict__ w1b,
                                               const float* __restrict__ fc1b,
                                               const bf16* __restrict__ zp,
                                               bf16* __restrict__ h1b) {
  __shared__ bf16 lsA[128 * 32];  // 8KB
  __shared__ bf16 lsB[128 * 32];  // 8KB
  const int tid = threadIdx.x;
  const int lane = tid & 63, wave = tid >> 6;
  const int row0 = blockIdx.x * 128;   // token base
  const int col0 = blockIdx.y * 128;   // channel base

  f32x4 acc[4][4] = {};
  const int wr = wave >> 1, wc = wave & 1;
  const int rl = lane & 15, kb = (lane >> 4) * 8;

  for (int ks = 0; ks < 5; ++ks) {
    __syncthreads();
    const int s = ks - 2;  // shift for channel chunk ks (32 channels each)
    // stage A (128x32): chunk c = issue*256+tid -> row=c>>2, kcol=(c&3)*8
#pragma unroll
    for (int issue = 0; issue < 2; ++issue) {
      int c = issue * 256 + tid;
      int ar = c >> 2;
      int kc = (c & 3) * 8;
      int t = row0 + ar;
      int h = (t >> 10) & 31;
      int hs = h - s;
      const bf16* src;
      if (hs >= 0 && hs < 32)
        src = xb + (size_t)(t - s * 1024) * CIN + ks * 32 + kc;
      else
        src = zp + (size_t)(c & 63) * 8;
      async16(src, (char*)lsA + issue * 4096 + wave * 1024);
    }
    // stage B (128x32) from w1b rows col0+row
#pragma unroll
    for (int issue = 0; issue < 2; ++issue) {
      int c = issue * 256 + tid;
      int br = c >> 2;
      int kc = (c & 3) * 8;
      const bf16* src = w1b + (size_t)(col0 + br) * CIN + ks * 32 + kc;
      async16(src, (char*)lsB + issue * 4096 + wave * 1024);
    }
    __syncthreads();
    bf16x8 af[4], bfr[4];
#pragma unroll
    for (int mi = 0; mi < 4; ++mi)
      af[mi] = *(const bf16x8*)&lsA[(wr * 64 + mi * 16 + rl) * 32 + kb];
#pragma unroll
    for (int ni = 0; ni < 4; ++ni)
      bfr[ni] = *(const bf16x8*)&lsB[(wc * 64 + ni * 16 + rl) * 32 + kb];
#pragma unroll
    for (int mi = 0; mi < 4; ++mi)
#pragma unroll
      for (int ni = 0; ni < 4; ++ni)
        acc[mi][ni] = __builtin_amdgcn_mfma_f32_16x16x32_bf16(af[mi], bfr[ni], acc[mi][ni], 0, 0, 0);
  }
  // C write: row=(lane>>4)*4+r, col=lane&15  [m89-verified layout]
  const int rq = lane >> 4;
#pragma unroll
  for (int mi = 0; mi < 4; ++mi) {
#pragma unroll
    for (int ni = 0; ni < 4; ++ni) {
      int col = col0 + wc * 64 + ni * 16 + rl;
      float bias = fc1b[col];
#pragma unroll
      for (int r = 0; r < 4; ++r) {
        int row = row0 + wr * 64 + mi * 16 + rq * 4 + r;
        h1b[(size_t)row * CHH + col] = (bf16)(acc[mi][ni][r] + bias);
      }
    }
  }
}

// ---- depthwise 3x3x3 conv + bias + exact GELU (v2: LDS weights, line-tiled) ----
// block = 256 threads = 8 c8-groups x 32 d. grid = (BN/32 lines, 10 ch-groups).
// Each block: one (b,h,w) d-line (32 tokens) x 64 channels; weights staged in LDS.
__global__ __launch_bounds__(256) void k_conv(const bf16* __restrict__ h1b,
                                              const float* __restrict__ wT,
                                              const float* __restrict__ dwb,
                                              bf16* __restrict__ h2b) {
  __shared__ float lw[27 * 64];  // 6.75KB: [tap][64ch]
  __shared__ float lb[64];
  const int tid = threadIdx.x;
  const int line = blockIdx.x;   // 0..2047 = b*1024 + h*32 + w
  const int cg = blockIdx.y;     // 0..9 (64-channel group)
#pragma unroll
  for (int i = 0; i < 7; ++i) {
    int idx = i * 256 + tid;
    if (idx < 27 * 64) {
      int tap = idx >> 6, ch = idx & 63;
      lw[idx] = wT[tap * CHH + cg * 64 + ch];
    }
  }
  if (tid < 64) lb[tid] = dwb[cg * 64 + tid];
  __syncthreads();

  const int c8 = tid & 7, d = tid >> 3;
  const int ch0 = cg * 64 + c8 * 8;
  const int w = line & 31, h = (line >> 5) & 31;
  const int t = line * 32 + d;

  float acc[8];
  {
    const float4 ba = *(const float4*)&lb[c8 * 8];
    const float4 bb = *(const float4*)&lb[c8 * 8 + 4];
    acc[0] = ba.x; acc[1] = ba.y; acc[2] = ba.z; acc[3] = ba.w;
    acc[4] = bb.x; acc[5] = bb.y; acc[6] = bb.z; acc[7] = bb.w;
  }
#pragma unroll
  for (int kz = 0; kz < 3; ++kz) {
    int hz = h + kz - 1;                 // block-uniform branch
    if ((unsigned)hz >= 32u) continue;
#pragma unroll
    for (int ky = 0; ky < 3; ++ky) {
      int wy = w + ky - 1;               // block-uniform branch
      if ((unsigned)wy >= 32u) continue;
#pragma unroll
      for (int kx = 0; kx < 3; ++kx) {
        int dx = d + kx - 1;             // per-thread only at d edges
        if ((unsigned)dx >= 32u) continue;
        int tap = kz * 9 + ky * 3 + kx;
        int ts = t + (kz - 1) * 1024 + (ky - 1) * 32 + (kx - 1);
        bf16x8 v = *(const bf16x8*)&h1b[(size_t)ts * CHH + ch0];
        const float4 wa = *(const float4*)&lw[tap * 64 + c8 * 8];
        const float4 wb = *(const float4*)&lw[tap * 64 + c8 * 8 + 4];
        acc[0] += (float)v[0] * wa.x; acc[1] += (float)v[1] * wa.y;
        acc[2] += (float)v[2] * wa.z; acc[3] += (float)v[3] * wa.w;
        acc[4] += (float)v[4] * wb.x; acc[5] += (float)v[5] * wb.y;
        acc[6] += (float)v[6] * wb.z; acc[7] += (float)v[7] * wb.w;
      }
    }
  }
  bf16x8 o;
#pragma unroll
  for (int j = 0; j < 8; ++j) {
    float xv = acc[j];
    float gel = 0.5f * xv * (1.0f + erff(xv * 0.70710678118654752f));
    o[j] = (bf16)gel;
  }
  *(bf16x8*)&h2b[(size_t)t * CHH + ch0] = o;
}

// ---- GEMM2: out[t,o] = sum_ch hs[t,ch] * fc2_w[o,ch] + fc2_b[o], shift(W) fused ----
// tile 128(M) x 160(N full), BK=64, K=640 (10 steps). 4 waves, each 32x160 (2x10 frags).
__global__ __launch_bounds__(256) void k_gemm2(const bf16* __restrict__ h2b,
                                               const bf16* __restrict__ w2b,
                                               const float* __restrict__ fc2b,
                                               const bf16* __restrict__ zp,
                                               float* __restrict__ out) {
  __shared__ bf16 lsA[128 * 64];  // 16KB
  __shared__ bf16 lsB[160 * 64];  // 20KB
  const int tid = threadIdx.x, lane = tid & 63, wave = tid >> 6;
  const int row0 = blockIdx.x * 128;
  const int rl = lane & 15, kb = (lane >> 4) * 8;

  f32x4 acc[2][10] = {};

  for (int kt = 0; kt < 10; ++kt) {
    __syncthreads();
    const int k0 = kt * 64;
    const int s = (k0 >> 7) - 2;  // shift for 128-channel chunk; uniform per 64-K slice
    // stage A (128x64): 1024 chunks = 4 issues; c -> row=c>>3, kcol=(c&7)*8
#pragma unroll
    for (int issue = 0; issue < 4; ++issue) {
      int c = issue * 256 + tid;
      int ar = c >> 3;
      int kc = (c & 7) * 8;
      int t = row0 + ar;
      int w = (t >> 5) & 31;
      int wsv = w - s;
      const bf16* src;
      if (wsv >= 0 && wsv < 32)
        src = h2b + (size_t)(t - s * 32) * CHH + k0 + kc;
      else
        src = zp + (size_t)(c & 63) * 8;
      async16(src, (char*)lsA + issue * 4096 + wave * 1024);
    }
    // stage B (160x64): 1280 chunks = 5 issues
#pragma unroll
    for (int issue = 0; issue < 5; ++issue) {
      int c = issue * 256 + tid;
      int br = c >> 3;
      int kc = (c & 7) * 8;
      const bf16* src = w2b + (size_t)br * CHH + k0 + kc;
      async16(src, (char*)lsB + issue * 4096 + wave * 1024);
    }
    __syncthreads();
#pragma unroll
    for (int kk = 0; kk < 2; ++kk) {
      bf16x8 af[2], bfr[10];
#pragma unroll
      for (int mi = 0; mi < 2; ++mi)
        af[mi] = *(const bf16x8*)&lsA[(wave * 32 + mi * 16 + rl) * 64 + kk * 32 + kb];
#pragma unroll
      for (int ni = 0; ni < 10; ++ni)
        bfr[ni] = *(const bf16x8*)&lsB[(ni * 16 + rl) * 64 + kk * 32 + kb];
#pragma unroll
      for (int mi = 0; mi < 2; ++mi)
#pragma unroll
        for (int ni = 0; ni < 10; ++ni)
          acc[mi][ni] = __builtin_amdgcn_mfma_f32_16x16x32_bf16(af[mi], bfr[ni], acc[mi][ni], 0, 0, 0);
    }
  }
  const int rq = lane >> 4;
#pragma unroll
  for (int mi = 0; mi < 2; ++mi) {
#pragma unroll
    for (int ni = 0; ni < 10; ++ni) {
      int col = ni * 16 + rl;
      float bias = fc2b[col];
#pragma unroll
      for (int r = 0; r < 4; ++r) {
        int row = row0 + wave * 32 + mi * 16 + rq * 4 + r;
        out[(size_t)row * CIN + col] = acc[mi][ni][r] + bias;
      }
    }
  }
}

extern "C" void kernel_launch(void* const* d_in, const int* in_sizes, int n_in,
                              void* d_out, int out_size, void* d_ws, size_t ws_size,
                              hipStream_t stream) {
  const float* x    = (const float*)d_in[0];
  const float* fc1w = (const float*)d_in[1];
  const float* fc1b = (const float*)d_in[2];
  const float* dww  = (const float*)d_in[3];
  const float* dwb  = (const float*)d_in[4];
  const float* fc2w = (const float*)d_in[5];
  const float* fc2b = (const float*)d_in[6];

  char* ws = (char*)d_ws;
  bf16* xb   = (bf16*)(ws + XB_OFF);
  bf16* w1b  = (bf16*)(ws + W1_OFF);
  bf16* w2b  = (bf16*)(ws + W2_OFF);
  float* wT  = (float*)(ws + WT_OFF);
  bf16* zp   = (bf16*)(ws + ZP_OFF);
  bf16* h1b  = (bf16*)(ws + H1_OFF);
  bf16* h2b  = (bf16*)(ws + H2_OFF);
  float* out = (float*)d_out;

  k_prep_x<<<(BN * CIN / 4) / 256, 256, 0, stream>>>(x, xb, BN * CIN / 4);
  k_prep_w<<<876, 256, 0, stream>>>(fc1w, fc2w, dww, w1b, w2b, wT, (unsigned*)zp);
  dim3 g1(512, 5);
  k_gemm1<<<g1, 256, 0, stream>>>(xb, w1b, fc1b, zp, h1b);
  dim3 gc(BN / 32, 10);
  k_conv<<<gc, 256, 0, stream>>>(h1b, wT, dwb, h2b);
  k_gemm2<<<512, 256, 0, stream>>>(h2b, w2b, fc2b, zp, out);
}

// Round 3
// 191.296 us; speedup vs baseline: 1.5799x; 1.0787x over previous
//
#include <hip/hip_runtime.h>
#include <hip/hip_bf16.h>
#include <math.h>

#define DEVI __device__ __forceinline__

typedef __bf16 bf16;
typedef _Float16 f16;
typedef bf16 bf16x4 __attribute__((ext_vector_type(4)));
typedef bf16 bf16x8 __attribute__((ext_vector_type(8)));
typedef f16 f16x2 __attribute__((ext_vector_type(2)));
typedef f16 f16x8 __attribute__((ext_vector_type(8)));
typedef float f32x4 __attribute__((ext_vector_type(4)));

// ---- problem dims (fixed) ----
constexpr int Bb = 2, Hh = 32, Ww = 32, Dd = 32;
constexpr int Nn = Hh * Ww * Dd;      // 32768
constexpr int BN = Bb * Nn;           // 65536 tokens
constexpr int CIN = 160, CHH = 640;

// ---- workspace layout (bytes, all 256-aligned) ----
constexpr size_t XB_OFF = 0;                                  // x as bf16: 20,971,520
constexpr size_t W1_OFF = XB_OFF + (size_t)BN * CIN * 2;      // fc1_w bf16: 204,800
constexpr size_t W2_OFF = W1_OFF + (size_t)CHH * CIN * 2;     // fc2_w bf16: 204,800
constexpr size_t WTH_OFF = W2_OFF + (size_t)CIN * CHH * 2;    // dw_w transposed f16 [27][640]: 34,560
constexpr size_t ZP_OFF = WTH_OFF + 34816;                    // zero page: 8192
constexpr size_t H1_OFF = ZP_OFF + 8192;                      // h1 f16: 83,886,080
constexpr size_t H2_OFF = H1_OFF + (size_t)BN * CHH * 2;      // h2 bf16: 83,886,080

DEVI void async16(const void* g, void* l) {
  __builtin_amdgcn_global_load_lds(
      (const __attribute__((address_space(1))) void*)g,
      (__attribute__((address_space(3))) void*)l, 16, 0, 0);
}

// ---- prep: x -> bf16 ----
__global__ __launch_bounds__(256) void k_prep_x(const float* __restrict__ x,
                                                bf16* __restrict__ xb, int n4) {
  int i = blockIdx.x * 256 + threadIdx.x;
  if (i >= n4) return;
  float4 v = reinterpret_cast<const float4*>(x)[i];
  bf16x4 o;
  o[0] = (bf16)v.x; o[1] = (bf16)v.y; o[2] = (bf16)v.z; o[3] = (bf16)v.w;
  reinterpret_cast<bf16x4*>(xb)[i] = o;
}

// ---- prep: weights -> bf16, dw_w transpose -> f16, zero page ----
__global__ __launch_bounds__(256) void k_prep_w(const float* __restrict__ fc1w,
                                                const float* __restrict__ fc2w,
                                                const float* __restrict__ dww,
                                                bf16* __restrict__ w1b,
                                                bf16* __restrict__ w2b,
                                                f16* __restrict__ wTh,
                                                unsigned* __restrict__ zp) {
  int i = blockIdx.x * 256 + threadIdx.x;
  const int NW = CHH * CIN;  // 102400
  if (i < NW) {
    w1b[i] = (bf16)fc1w[i];
  } else if (i < 2 * NW) {
    int j = i - NW;
    w2b[j] = (bf16)fc2w[j];
  } else if (i < 2 * NW + 27 * CHH) {
    int j = i - 2 * NW;
    int ch = j / 27, tap = j % 27;
    wTh[tap * CHH + ch] = (f16)dww[j];
  } else if (i < 2 * NW + 27 * CHH + 2048) {
    zp[i - (2 * NW + 27 * CHH)] = 0u;
  }
}

// ---- GEMM1: h1[t,ch] = sum_c xs[t,c] * fc1_w[ch,c] + fc1_b[ch], shift(H) fused ----
// tile 128(M) x 128(N), BK=32, K=160 (5 steps). 4 waves, each 64x64 (4x4 frags). Output f16.
__global__ __launch_bounds__(256) void k_gemm1(const bf16* __restrict__ xb,
                                               const bf16* __restrict__ w1b,
                                               const float* __restrict__ fc1b,
                                               const bf16* __restrict__ zp,
                                               f16* __restrict__ h1h) {
  __shared__ bf16 lsA[128 * 32];  // 8KB
  __shared__ bf16 lsB[128 * 32];  // 8KB
  const int tid = threadIdx.x;
  const int lane = tid & 63, wave = tid >> 6;
  const int row0 = blockIdx.x * 128;   // token base
  const int col0 = blockIdx.y * 128;   // channel base

  f32x4 acc[4][4] = {};
  const int wr = wave >> 1, wc = wave & 1;
  const int rl = lane & 15, kb = (lane >> 4) * 8;

  for (int ks = 0; ks < 5; ++ks) {
    __syncthreads();
    const int s = ks - 2;  // shift for channel chunk ks (32 channels each)
#pragma unroll
    for (int issue = 0; issue < 2; ++issue) {
      int c = issue * 256 + tid;
      int ar = c >> 2;
      int kc = (c & 3) * 8;
      int t = row0 + ar;
      int h = (t >> 10) & 31;
      int hs = h - s;
      const bf16* src;
      if (hs >= 0 && hs < 32)
        src = xb + (size_t)(t - s * 1024) * CIN + ks * 32 + kc;
      else
        src = zp + (size_t)(c & 63) * 8;
      async16(src, (char*)lsA + issue * 4096 + wave * 1024);
    }
#pragma unroll
    for (int issue = 0; issue < 2; ++issue) {
      int c = issue * 256 + tid;
      int br = c >> 2;
      int kc = (c & 3) * 8;
      const bf16* src = w1b + (size_t)(col0 + br) * CIN + ks * 32 + kc;
      async16(src, (char*)lsB + issue * 4096 + wave * 1024);
    }
    __syncthreads();
    bf16x8 af[4], bfr[4];
#pragma unroll
    for (int mi = 0; mi < 4; ++mi)
      af[mi] = *(const bf16x8*)&lsA[(wr * 64 + mi * 16 + rl) * 32 + kb];
#pragma unroll
    for (int ni = 0; ni < 4; ++ni)
      bfr[ni] = *(const bf16x8*)&lsB[(wc * 64 + ni * 16 + rl) * 32 + kb];
#pragma unroll
    for (int mi = 0; mi < 4; ++mi)
#pragma unroll
      for (int ni = 0; ni < 4; ++ni)
        acc[mi][ni] = __builtin_amdgcn_mfma_f32_16x16x32_bf16(af[mi], bfr[ni], acc[mi][ni], 0, 0, 0);
  }
  const int rq = lane >> 4;
#pragma unroll
  for (int mi = 0; mi < 4; ++mi) {
#pragma unroll
    for (int ni = 0; ni < 4; ++ni) {
      int col = col0 + wc * 64 + ni * 16 + rl;
      float bias = fc1b[col];
#pragma unroll
      for (int r = 0; r < 4; ++r) {
        int row = row0 + wr * 64 + mi * 16 + rq * 4 + r;
        h1h[(size_t)row * CHH + col] = (f16)(acc[mi][ni][r] + bias);
      }
    }
  }
}

// ---- depthwise 3x3x3 conv + bias + exact GELU (v3: packed f16 MACs) ----
// block = 256 threads = 8 c8-groups x 32 d. grid = (BN/32 lines, 10 ch-groups).
// Per tap per 8 channels: 4x v_pk_fma_f16 (f16 acc, no converts in loop).
__global__ __launch_bounds__(256) void k_conv(const f16* __restrict__ h1h,
                                              const f16* __restrict__ wTh,
                                              const float* __restrict__ dwb,
                                              bf16* __restrict__ h2b) {
  __shared__ f16 lw[27 * 64];   // 3.375KB: [tap][64ch] packed f16
  __shared__ float lb[64];
  const int tid = threadIdx.x;
  const int line = blockIdx.x;   // 0..2047 = b*1024 + h*32 + w
  const int cg = blockIdx.y;     // 0..9 (64-channel group)
#pragma unroll
  for (int i = 0; i < 7; ++i) {
    int idx = i * 256 + tid;
    if (idx < 27 * 64) {
      int tap = idx >> 6, ch = idx & 63;
      lw[idx] = wTh[tap * CHH + cg * 64 + ch];
    }
  }
  if (tid < 64) lb[tid] = dwb[cg * 64 + tid];
  __syncthreads();

  const int c8 = tid & 7, d = tid >> 3;
  const int ch0 = cg * 64 + c8 * 8;
  const int w = line & 31, h = (line >> 5) & 31;
  const int t = line * 32 + d;
  const f16* base = h1h + (size_t)t * CHH + ch0;

  f16x8 acc;
#pragma unroll
  for (int j = 0; j < 8; ++j) acc[j] = (f16)lb[c8 * 8 + j];

#pragma unroll
  for (int kz = 0; kz < 3; ++kz) {
    int hz = h + kz - 1;                 // block-uniform branch
    if ((unsigned)hz >= 32u) continue;
#pragma unroll
    for (int ky = 0; ky < 3; ++ky) {
      int wy = w + ky - 1;               // block-uniform branch
      if ((unsigned)wy >= 32u) continue;
#pragma unroll
      for (int kx = 0; kx < 3; ++kx) {
        int dx = d + kx - 1;             // per-thread only at d edges
        if ((unsigned)dx >= 32u) continue;
        const int off = ((kz - 1) * 1024 + (ky - 1) * 32 + (kx - 1)) * CHH;
        f16x8 v = *(const f16x8*)(base + off);
        f16x8 wv = *(const f16x8*)&lw[(kz * 9 + ky * 3 + kx) * 64 + c8 * 8];
        acc = v * wv + acc;              // 4x v_pk_fma_f16
      }
    }
  }
  bf16x8 o;
#pragma unroll
  for (int j = 0; j < 8; ++j) {
    float xv = (float)acc[j];
    float gel = 0.5f * xv * (1.0f + erff(xv * 0.70710678118654752f));
    o[j] = (bf16)gel;
  }
  *(bf16x8*)&h2b[(size_t)t * CHH + ch0] = o;
}

// ---- GEMM2: out[t,o] = sum_ch hs[t,ch] * fc2_w[o,ch] + fc2_b[o], shift(W) fused ----
// tile 128(M) x 160(N full), BK=64, K=640 (10 steps). 4 waves, each 32x160 (2x10 frags).
__global__ __launch_bounds__(256) void k_gemm2(const bf16* __restrict__ h2b,
                                               const bf16* __restrict__ w2b,
                                               const float* __restrict__ fc2b,
                                               const bf16* __restrict__ zp,
                                               float* __restrict__ out) {
  __shared__ bf16 lsA[128 * 64];  // 16KB
  __shared__ bf16 lsB[160 * 64];  // 20KB
  const int tid = threadIdx.x, lane = tid & 63, wave = tid >> 6;
  const int row0 = blockIdx.x * 128;
  const int rl = lane & 15, kb = (lane >> 4) * 8;

  f32x4 acc[2][10] = {};

  for (int kt = 0; kt < 10; ++kt) {
    __syncthreads();
    const int k0 = kt * 64;
    const int s = (k0 >> 7) - 2;  // shift for 128-channel chunk; uniform per 64-K slice
#pragma unroll
    for (int issue = 0; issue < 4; ++issue) {
      int c = issue * 256 + tid;
      int ar = c >> 3;
      int kc = (c & 7) * 8;
      int t = row0 + ar;
      int w = (t >> 5) & 31;
      int wsv = w - s;
      const bf16* src;
      if (wsv >= 0 && wsv < 32)
        src = h2b + (size_t)(t - s * 32) * CHH + k0 + kc;
      else
        src = zp + (size_t)(c & 63) * 8;
      async16(src, (char*)lsA + issue * 4096 + wave * 1024);
    }
#pragma unroll
    for (int issue = 0; issue < 5; ++issue) {
      int c = issue * 256 + tid;
      int br = c >> 3;
      int kc = (c & 7) * 8;
      const bf16* src = w2b + (size_t)br * CHH + k0 + kc;
      async16(src, (char*)lsB + issue * 4096 + wave * 1024);
    }
    __syncthreads();
#pragma unroll
    for (int kk = 0; kk < 2; ++kk) {
      bf16x8 af[2], bfr[10];
#pragma unroll
      for (int mi = 0; mi < 2; ++mi)
        af[mi] = *(const bf16x8*)&lsA[(wave * 32 + mi * 16 + rl) * 64 + kk * 32 + kb];
#pragma unroll
      for (int ni = 0; ni < 10; ++ni)
        bfr[ni] = *(const bf16x8*)&lsB[(ni * 16 + rl) * 64 + kk * 32 + kb];
#pragma unroll
      for (int mi = 0; mi < 2; ++mi)
#pragma unroll
        for (int ni = 0; ni < 10; ++ni)
          acc[mi][ni] = __builtin_amdgcn_mfma_f32_16x16x32_bf16(af[mi], bfr[ni], acc[mi][ni], 0, 0, 0);
    }
  }
  const int rq = lane >> 4;
#pragma unroll
  for (int mi = 0; mi < 2; ++mi) {
#pragma unroll
    for (int ni = 0; ni < 10; ++ni) {
      int col = ni * 16 + rl;
      float bias = fc2b[col];
#pragma unroll
      for (int r = 0; r < 4; ++r) {
        int row = row0 + wave * 32 + mi * 16 + rq * 4 + r;
        out[(size_t)row * CIN + col] = acc[mi][ni][r] + bias;
      }
    }
  }
}

extern "C" void kernel_launch(void* const* d_in, const int* in_sizes, int n_in,
                              void* d_out, int out_size, void* d_ws, size_t ws_size,
                              hipStream_t stream) {
  const float* x    = (const float*)d_in[0];
  const float* fc1w = (const float*)d_in[1];
  const float* fc1b = (const float*)d_in[2];
  const float* dww  = (const float*)d_in[3];
  const float* dwb  = (const float*)d_in[4];
  const float* fc2w = (const float*)d_in[5];
  const float* fc2b = (const float*)d_in[6];

  char* ws = (char*)d_ws;
  bf16* xb   = (bf16*)(ws + XB_OFF);
  bf16* w1b  = (bf16*)(ws + W1_OFF);
  bf16* w2b  = (bf16*)(ws + W2_OFF);
  f16*  wTh  = (f16*)(ws + WTH_OFF);
  bf16* zp   = (bf16*)(ws + ZP_OFF);
  f16*  h1h  = (f16*)(ws + H1_OFF);
  bf16* h2b  = (bf16*)(ws + H2_OFF);
  float* out = (float*)d_out;

  k_prep_x<<<(BN * CIN / 4) / 256, 256, 0, stream>>>(x, xb, BN * CIN / 4);
  k_prep_w<<<943, 256, 0, stream>>>(fc1w, fc2w, dww, w1b, w2b, wTh, (unsigned*)zp);
  dim3 g1(512, 5);
  k_gemm1<<<g1, 256, 0, stream>>>(xb, w1b, fc1b, zp, h1h);
  dim3 gc(BN / 32, 10);
  k_conv<<<gc, 256, 0, stream>>>(h1h, wTh, dwb, h2b);
  k_gemm2<<<512, 256, 0, stream>>>(h2b, w2b, fc2b, zp, out);
}

// Round 4
// 146.633 us; speedup vs baseline: 2.0611x; 1.3046x over previous
//
#include <hip/hip_runtime.h>
#include <hip/hip_bf16.h>
#include <math.h>

#define DEVI __device__ __forceinline__

typedef __bf16 bf16;
typedef _Float16 f16;
typedef bf16 bf16x4 __attribute__((ext_vector_type(4)));
typedef bf16 bf16x8 __attribute__((ext_vector_type(8)));
typedef f16 f16x8 __attribute__((ext_vector_type(8)));
typedef float f32x4 __attribute__((ext_vector_type(4)));

// ---- problem dims (fixed) ----
constexpr int Bb = 2, Hh = 32, Ww = 32, Dd = 32;
constexpr int Nn = Hh * Ww * Dd;      // 32768
constexpr int BN = Bb * Nn;           // 65536 tokens
constexpr int CIN = 160, CHH = 640;

// ---- workspace layout (bytes, all 256-aligned) ----
constexpr size_t XB_OFF = 0;                                  // x as bf16: 20,971,520
constexpr size_t W1_OFF = XB_OFF + (size_t)BN * CIN * 2;      // fc1_w bf16: 204,800
constexpr size_t W2_OFF = W1_OFF + (size_t)CHH * CIN * 2;     // fc2_w bf16: 204,800
constexpr size_t WTH_OFF = W2_OFF + (size_t)CIN * CHH * 2;    // dw_w transposed f16 [27][640]: 34,560
constexpr size_t ZP_OFF = WTH_OFF + 34816;                    // zero page: 8192
constexpr size_t H1_OFF = ZP_OFF + 8192;                      // h1 f16: 83,886,080
constexpr size_t H2_OFF = H1_OFF + (size_t)BN * CHH * 2;      // h2 bf16: 83,886,080

DEVI void async16(const void* g, void* l) {
  __builtin_amdgcn_global_load_lds(
      (const __attribute__((address_space(1))) void*)g,
      (__attribute__((address_space(3))) void*)l, 16, 0, 0);
}

// ---- prep: x -> bf16 ----
__global__ __launch_bounds__(256) void k_prep_x(const float* __restrict__ x,
                                                bf16* __restrict__ xb, int n4) {
  int i = blockIdx.x * 256 + threadIdx.x;
  if (i >= n4) return;
  float4 v = reinterpret_cast<const float4*>(x)[i];
  bf16x4 o;
  o[0] = (bf16)v.x; o[1] = (bf16)v.y; o[2] = (bf16)v.z; o[3] = (bf16)v.w;
  reinterpret_cast<bf16x4*>(xb)[i] = o;
}

// ---- prep: weights -> bf16, dw_w transpose -> f16, zero page ----
__global__ __launch_bounds__(256) void k_prep_w(const float* __restrict__ fc1w,
                                                const float* __restrict__ fc2w,
                                                const float* __restrict__ dww,
                                                bf16* __restrict__ w1b,
                                                bf16* __restrict__ w2b,
                                                f16* __restrict__ wTh,
                                                unsigned* __restrict__ zp) {
  int i = blockIdx.x * 256 + threadIdx.x;
  const int NW = CHH * CIN;  // 102400
  if (i < NW) {
    w1b[i] = (bf16)fc1w[i];
  } else if (i < 2 * NW) {
    int j = i - NW;
    w2b[j] = (bf16)fc2w[j];
  } else if (i < 2 * NW + 27 * CHH) {
    int j = i - 2 * NW;
    int ch = j / 27, tap = j % 27;
    wTh[tap * CHH + ch] = (f16)dww[j];
  } else if (i < 2 * NW + 27 * CHH + 2048) {
    zp[i - (2 * NW + 27 * CHH)] = 0u;
  }
}

// ---- GEMM1: h1[t,ch] = sum_c xs[t,c] * fc1_w[ch,c] + fc1_b[ch], shift(H) fused ----
// tile 128(M) x 128(N), BK=32, K=160 (5 steps). 4 waves, each 64x64 (4x4 frags). Output f16.
__global__ __launch_bounds__(256) void k_gemm1(const bf16* __restrict__ xb,
                                               const bf16* __restrict__ w1b,
                                               const float* __restrict__ fc1b,
                                               const bf16* __restrict__ zp,
                                               f16* __restrict__ h1h) {
  __shared__ bf16 lsA[128 * 32];  // 8KB
  __shared__ bf16 lsB[128 * 32];  // 8KB
  const int tid = threadIdx.x;
  const int lane = tid & 63, wave = tid >> 6;
  const int row0 = blockIdx.x * 128;   // token base
  const int col0 = blockIdx.y * 128;   // channel base

  f32x4 acc[4][4] = {};
  const int wr = wave >> 1, wc = wave & 1;
  const int rl = lane & 15, kb = (lane >> 4) * 8;

  for (int ks = 0; ks < 5; ++ks) {
    __syncthreads();
    const int s = ks - 2;  // shift for channel chunk ks (32 channels each)
#pragma unroll
    for (int issue = 0; issue < 2; ++issue) {
      int c = issue * 256 + tid;
      int ar = c >> 2;
      int kc = (c & 3) * 8;
      int t = row0 + ar;
      int h = (t >> 10) & 31;
      int hs = h - s;
      const bf16* src;
      if (hs >= 0 && hs < 32)
        src = xb + (size_t)(t - s * 1024) * CIN + ks * 32 + kc;
      else
        src = zp + (size_t)(c & 63) * 8;
      async16(src, (char*)lsA + issue * 4096 + wave * 1024);
    }
#pragma unroll
    for (int issue = 0; issue < 2; ++issue) {
      int c = issue * 256 + tid;
      int br = c >> 2;
      int kc = (c & 3) * 8;
      const bf16* src = w1b + (size_t)(col0 + br) * CIN + ks * 32 + kc;
      async16(src, (char*)lsB + issue * 4096 + wave * 1024);
    }
    __syncthreads();
    bf16x8 af[4], bfr[4];
#pragma unroll
    for (int mi = 0; mi < 4; ++mi)
      af[mi] = *(const bf16x8*)&lsA[(wr * 64 + mi * 16 + rl) * 32 + kb];
#pragma unroll
    for (int ni = 0; ni < 4; ++ni)
      bfr[ni] = *(const bf16x8*)&lsB[(wc * 64 + ni * 16 + rl) * 32 + kb];
#pragma unroll
    for (int mi = 0; mi < 4; ++mi)
#pragma unroll
      for (int ni = 0; ni < 4; ++ni)
        acc[mi][ni] = __builtin_amdgcn_mfma_f32_16x16x32_bf16(af[mi], bfr[ni], acc[mi][ni], 0, 0, 0);
  }
  const int rq = lane >> 4;
#pragma unroll
  for (int mi = 0; mi < 4; ++mi) {
#pragma unroll
    for (int ni = 0; ni < 4; ++ni) {
      int col = col0 + wc * 64 + ni * 16 + rl;
      float bias = fc1b[col];
#pragma unroll
      for (int r = 0; r < 4; ++r) {
        int row = row0 + wr * 64 + mi * 16 + rq * 4 + r;
        h1h[(size_t)row * CHH + col] = (f16)(acc[mi][ni][r] + bias);
      }
    }
  }
}

// ---- depthwise 3x3x3 conv + bias + GELU (v4: d-quad per thread, tanh gelu) ----
// block = 256 threads = 4 waves; wave = one (b,h,w) line: 8 c8 x 8 dq (4 d-outputs each).
// grid = (BN/32/4, 10 ch-groups). Weights in LDS, read 3/plane into regs.
__global__ __launch_bounds__(256) void k_conv(const f16* __restrict__ h1h,
                                              const f16* __restrict__ wTh,
                                              const float* __restrict__ dwb,
                                              const bf16* __restrict__ zp,
                                              bf16* __restrict__ h2b) {
  __shared__ f16 lw[27 * 64];   // 3.375KB: [tap][64ch]
  __shared__ float lb[64];
  const int tid = threadIdx.x;
  const int cg = blockIdx.y;     // 0..9 (64-channel group)
#pragma unroll
  for (int i = 0; i < 7; ++i) {
    int idx = i * 256 + tid;
    if (idx < 27 * 64) lw[idx] = wTh[(idx >> 6) * CHH + cg * 64 + (idx & 63)];
  }
  if (tid < 64) lb[tid] = dwb[cg * 64 + tid];
  __syncthreads();

  const int lane = tid & 63, wave = tid >> 6;
  const int line = blockIdx.x * 4 + wave;   // 0..2047 = b*1024 + h*32 + w
  const int c8 = lane & 7, dq = lane >> 3;  // dq in 0..7
  const int d0 = dq * 4;
  const int ch0 = cg * 64 + c8 * 8;
  const int w = line & 31, h = (line >> 5) & 31;
  const f16* zpf = (const f16*)zp;

  f16x8 acc[4];
  {
    f16x8 binit;
#pragma unroll
    for (int j = 0; j < 8; ++j) binit[j] = (f16)lb[c8 * 8 + j];
    acc[0] = binit; acc[1] = binit; acc[2] = binit; acc[3] = binit;
  }

  const ptrdiff_t base_line = (ptrdiff_t)line * 32 * CHH + ch0;

#pragma unroll
  for (int kz = 0; kz < 3; ++kz) {
    int hz = h + kz - 1;                 // wave-uniform branch
    if ((unsigned)hz >= 32u) continue;
#pragma unroll
    for (int ky = 0; ky < 3; ++ky) {
      int wy = w + ky - 1;               // wave-uniform branch
      if ((unsigned)wy >= 32u) continue;
      const f16* rowbase = h1h + base_line +
                           (ptrdiff_t)((kz - 1) * 1024 + (ky - 1) * 32) * CHH;
      f16x8 wt[3];
#pragma unroll
      for (int kx = 0; kx < 3; ++kx)
        wt[kx] = *(const f16x8*)&lw[((kz * 9 + ky * 3 + kx) << 6) + c8 * 8];
      f16x8 v[6];
#pragma unroll
      for (int j = 0; j < 6; ++j) {
        int td = d0 - 1 + j;
        const f16* p = ((unsigned)td < 32u) ? rowbase + (ptrdiff_t)td * CHH
                                            : zpf + c8 * 8;
        v[j] = *(const f16x8*)p;
      }
#pragma unroll
      for (int o = 0; o < 4; ++o)
#pragma unroll
        for (int kx = 0; kx < 3; ++kx)
          acc[o] = v[o + kx] * wt[kx] + acc[o];   // v_pk_fma_f16
    }
  }

#pragma unroll
  for (int o = 0; o < 4; ++o) {
    bf16x8 ovec;
#pragma unroll
    for (int j = 0; j < 8; ++j) {
      float xv = (float)acc[o][j];
      float zt = 0.7978845608f * xv + 0.03567740814f * (xv * xv * xv);
      zt = fminf(fmaxf(zt, -15.0f), 15.0f);
      float e = __builtin_exp2f(zt * 2.8853900817779268f);
      float tnh = (e - 1.0f) / (e + 1.0f);
      ovec[j] = (bf16)(0.5f * xv * (1.0f + tnh));
    }
    *(bf16x8*)&h2b[base_line + (ptrdiff_t)(d0 + o) * CHH] = ovec;
  }
}

// ---- GEMM2: out[t,o] = sum_ch hs[t,ch] * fc2_w[o,ch] + fc2_b[o], shift(W) fused ----
// tile 128(M) x 160(N full), BK=64, K=640 (10 steps). 4 waves, each 32x160 (2x10 frags).
__global__ __launch_bounds__(256) void k_gemm2(const bf16* __restrict__ h2b,
                                               const bf16* __restrict__ w2b,
                                               const float* __restrict__ fc2b,
                                               const bf16* __restrict__ zp,
                                               float* __restrict__ out) {
  __shared__ bf16 lsA[128 * 64];  // 16KB
  __shared__ bf16 lsB[160 * 64];  // 20KB
  const int tid = threadIdx.x, lane = tid & 63, wave = tid >> 6;
  const int row0 = blockIdx.x * 128;
  const int rl = lane & 15, kb = (lane >> 4) * 8;

  f32x4 acc[2][10] = {};

  for (int kt = 0; kt < 10; ++kt) {
    __syncthreads();
    const int k0 = kt * 64;
    const int s = (k0 >> 7) - 2;  // shift for 128-channel chunk; uniform per 64-K slice
#pragma unroll
    for (int issue = 0; issue < 4; ++issue) {
      int c = issue * 256 + tid;
      int ar = c >> 3;
      int kc = (c & 7) * 8;
      int t = row0 + ar;
      int w = (t >> 5) & 31;
      int wsv = w - s;
      const bf16* src;
      if (wsv >= 0 && wsv < 32)
        src = h2b + (size_t)(t - s * 32) * CHH + k0 + kc;
      else
        src = zp + (size_t)(c & 63) * 8;
      async16(src, (char*)lsA + issue * 4096 + wave * 1024);
    }
#pragma unroll
    for (int issue = 0; issue < 5; ++issue) {
      int c = issue * 256 + tid;
      int br = c >> 3;
      int kc = (c & 7) * 8;
      const bf16* src = w2b + (size_t)br * CHH + k0 + kc;
      async16(src, (char*)lsB + issue * 4096 + wave * 1024);
    }
    __syncthreads();
#pragma unroll
    for (int kk = 0; kk < 2; ++kk) {
      bf16x8 af[2], bfr[10];
#pragma unroll
      for (int mi = 0; mi < 2; ++mi)
        af[mi] = *(const bf16x8*)&lsA[(wave * 32 + mi * 16 + rl) * 64 + kk * 32 + kb];
#pragma unroll
      for (int ni = 0; ni < 10; ++ni)
        bfr[ni] = *(const bf16x8*)&lsB[(ni * 16 + rl) * 64 + kk * 32 + kb];
#pragma unroll
      for (int mi = 0; mi < 2; ++mi)
#pragma unroll
        for (int ni = 0; ni < 10; ++ni)
          acc[mi][ni] = __builtin_amdgcn_mfma_f32_16x16x32_bf16(af[mi], bfr[ni], acc[mi][ni], 0, 0, 0);
    }
  }
  const int rq = lane >> 4;
#pragma unroll
  for (int mi = 0; mi < 2; ++mi) {
#pragma unroll
    for (int ni = 0; ni < 10; ++ni) {
      int col = ni * 16 + rl;
      float bias = fc2b[col];
#pragma unroll
      for (int r = 0; r < 4; ++r) {
        int row = row0 + wave * 32 + mi * 16 + rq * 4 + r;
        out[(size_t)row * CIN + col] = acc[mi][ni][r] + bias;
      }
    }
  }
}

extern "C" void kernel_launch(void* const* d_in, const int* in_sizes, int n_in,
                              void* d_out, int out_size, void* d_ws, size_t ws_size,
                              hipStream_t stream) {
  const float* x    = (const float*)d_in[0];
  const float* fc1w = (const float*)d_in[1];
  const float* fc1b = (const float*)d_in[2];
  const float* dww  = (const float*)d_in[3];
  const float* dwb  = (const float*)d_in[4];
  const float* fc2w = (const float*)d_in[5];
  const float* fc2b = (const float*)d_in[6];

  char* ws = (char*)d_ws;
  bf16* xb   = (bf16*)(ws + XB_OFF);
  bf16* w1b  = (bf16*)(ws + W1_OFF);
  bf16* w2b  = (bf16*)(ws + W2_OFF);
  f16*  wTh  = (f16*)(ws + WTH_OFF);
  bf16* zp   = (bf16*)(ws + ZP_OFF);
  f16*  h1h  = (f16*)(ws + H1_OFF);
  bf16* h2b  = (bf16*)(ws + H2_OFF);
  float* out = (float*)d_out;

  k_prep_x<<<(BN * CIN / 4) / 256, 256, 0, stream>>>(x, xb, BN * CIN / 4);
  k_prep_w<<<943, 256, 0, stream>>>(fc1w, fc2w, dww, w1b, w2b, wTh, (unsigned*)zp);
  dim3 g1(512, 5);
  k_gemm1<<<g1, 256, 0, stream>>>(xb, w1b, fc1b, zp, h1h);
  dim3 gc(BN / 32 / 4, 10);
  k_conv<<<gc, 256, 0, stream>>>(h1h, wTh, dwb, zp, h2b);
  k_gemm2<<<512, 256, 0, stream>>>(h2b, w2b, fc2b, zp, out);
}

// Round 5
// 145.968 us; speedup vs baseline: 2.0705x; 1.0046x over previous
//
#include <hip/hip_runtime.h>
#include <hip/hip_bf16.h>
#include <math.h>

#define DEVI __device__ __forceinline__

typedef __bf16 bf16;
typedef _Float16 f16;
typedef bf16 bf16x4 __attribute__((ext_vector_type(4)));
typedef bf16 bf16x8 __attribute__((ext_vector_type(8)));
typedef f16 f16x8 __attribute__((ext_vector_type(8)));
typedef float f32x4 __attribute__((ext_vector_type(4)));

// ---- problem dims (fixed) ----
constexpr int Bb = 2, Hh = 32, Ww = 32, Dd = 32;
constexpr int Nn = Hh * Ww * Dd;      // 32768
constexpr int BN = Bb * Nn;           // 65536 tokens
constexpr int CIN = 160, CHH = 640;
constexpr int PD = 34;                // padded dim
constexpr int PT = PD * PD * PD;      // 39304 padded tokens per batch

// ---- workspace layout (bytes) ----
// [weights | U: union(xb, h2) | h1 padded]  -- xb dead after gemm1, h2 written by conv
constexpr size_t W1_OFF  = 0;                                   // fc1_w bf16: 204,800
constexpr size_t W2_OFF  = W1_OFF + (size_t)CHH * CIN * 2;      // fc2_w bf16: 204,800
constexpr size_t WTH_OFF = W2_OFF + (size_t)CIN * CHH * 2;      // dw_w f16 [27][640]: 34,560
constexpr size_t ZP_OFF  = WTH_OFF + 34816;                     // zero page: 8,192
constexpr size_t U_OFF   = 458752;                              // union region
constexpr size_t H1P_OFF = U_OFF + (size_t)BN * CHH * 2;        // h1 padded f16: 100,618,240
// total ~185 MB

DEVI void async16(const void* g, void* l) {
  __builtin_amdgcn_global_load_lds(
      (const __attribute__((address_space(1))) void*)g,
      (__attribute__((address_space(3))) void*)l, 16, 0, 0);
}

// ---- prep: x -> bf16 ----
__global__ __launch_bounds__(256) void k_prep_x(const float* __restrict__ x,
                                                bf16* __restrict__ xb, int n4) {
  int i = blockIdx.x * 256 + threadIdx.x;
  if (i >= n4) return;
  float4 v = reinterpret_cast<const float4*>(x)[i];
  bf16x4 o;
  o[0] = (bf16)v.x; o[1] = (bf16)v.y; o[2] = (bf16)v.z; o[3] = (bf16)v.w;
  reinterpret_cast<bf16x4*>(xb)[i] = o;
}

// ---- prep: weights -> bf16, dw_w transpose -> f16, zero page ----
__global__ __launch_bounds__(256) void k_prep_w(const float* __restrict__ fc1w,
                                                const float* __restrict__ fc2w,
                                                const float* __restrict__ dww,
                                                bf16* __restrict__ w1b,
                                                bf16* __restrict__ w2b,
                                                f16* __restrict__ wTh,
                                                unsigned* __restrict__ zp) {
  int i = blockIdx.x * 256 + threadIdx.x;
  const int NW = CHH * CIN;  // 102400
  if (i < NW) {
    w1b[i] = (bf16)fc1w[i];
  } else if (i < 2 * NW) {
    int j = i - NW;
    w2b[j] = (bf16)fc2w[j];
  } else if (i < 2 * NW + 27 * CHH) {
    int j = i - 2 * NW;
    int ch = j / 27, tap = j % 27;
    wTh[tap * CHH + ch] = (f16)dww[j];
  } else if (i < 2 * NW + 27 * CHH + 2048) {
    zp[i - (2 * NW + 27 * CHH)] = 0u;
  }
}

// ---- zero the pad shell of the padded h1 volume (no input deps) ----
__global__ __launch_bounds__(256) void k_zero_pad(f16* __restrict__ h1p) {
  int g = blockIdx.x * 256 + threadIdx.x;   // over 2*PT*80
  int p = g / 80;
  int c = g - p * 80;
  if (p >= 2 * PT) return;
  int r = p % PT;
  int hp = r / (PD * PD);
  int r2 = r % (PD * PD);
  int wp = r2 / PD, dp = r2 % PD;
  bool pad = (hp == 0) | (hp == PD - 1) | (wp == 0) | (wp == PD - 1) |
             (dp == 0) | (dp == PD - 1);
  if (!pad) return;
  f16x8 z = {};
  *(f16x8*)&h1p[(size_t)p * CHH + c * 8] = z;
}

// ---- GEMM1: h1p[pad(t),ch] = sum_c xs[t,c]*fc1_w[ch,c] + b, shift(H) fused ----
// tile 128x128, BK=32, K=160. Output written into padded f16 volume.
__global__ __launch_bounds__(256) void k_gemm1(const bf16* __restrict__ xb,
                                               const bf16* __restrict__ w1b,
                                               const float* __restrict__ fc1b,
                                               const bf16* __restrict__ zp,
                                               f16* __restrict__ h1p) {
  __shared__ bf16 lsA[128 * 32];  // 8KB
  __shared__ bf16 lsB[128 * 32];  // 8KB
  const int tid = threadIdx.x;
  const int lane = tid & 63, wave = tid >> 6;
  const int row0 = blockIdx.x * 128;   // token base
  const int col0 = blockIdx.y * 128;   // channel base

  f32x4 acc[4][4] = {};
  const int wr = wave >> 1, wc = wave & 1;
  const int rl = lane & 15, kb = (lane >> 4) * 8;

  for (int ks = 0; ks < 5; ++ks) {
    __syncthreads();
    const int s = ks - 2;  // shift for channel chunk ks (32 channels each)
#pragma unroll
    for (int issue = 0; issue < 2; ++issue) {
      int c = issue * 256 + tid;
      int ar = c >> 2;
      int kc = (c & 3) * 8;
      int t = row0 + ar;
      int h = (t >> 10) & 31;
      int hs = h - s;
      const bf16* src;
      if (hs >= 0 && hs < 32)
        src = xb + (size_t)(t - s * 1024) * CIN + ks * 32 + kc;
      else
        src = zp + (size_t)(c & 63) * 8;
      async16(src, (char*)lsA + issue * 4096 + wave * 1024);
    }
#pragma unroll
    for (int issue = 0; issue < 2; ++issue) {
      int c = issue * 256 + tid;
      int br = c >> 2;
      int kc = (c & 3) * 8;
      const bf16* src = w1b + (size_t)(col0 + br) * CIN + ks * 32 + kc;
      async16(src, (char*)lsB + issue * 4096 + wave * 1024);
    }
    __syncthreads();
    bf16x8 af[4], bfr[4];
#pragma unroll
    for (int mi = 0; mi < 4; ++mi)
      af[mi] = *(const bf16x8*)&lsA[(wr * 64 + mi * 16 + rl) * 32 + kb];
#pragma unroll
    for (int ni = 0; ni < 4; ++ni)
      bfr[ni] = *(const bf16x8*)&lsB[(wc * 64 + ni * 16 + rl) * 32 + kb];
#pragma unroll
    for (int mi = 0; mi < 4; ++mi)
#pragma unroll
      for (int ni = 0; ni < 4; ++ni)
        acc[mi][ni] = __builtin_amdgcn_mfma_f32_16x16x32_bf16(af[mi], bfr[ni], acc[mi][ni], 0, 0, 0);
  }
  // epilogue: padded write. 4-row quads are d-aligned -> one addr calc per quad.
  const int rq = lane >> 4;
#pragma unroll
  for (int mi = 0; mi < 4; ++mi) {
    int rowq = row0 + wr * 64 + mi * 16 + rq * 4;
    int bq = rowq >> 15;
    int nq = rowq & 32767;
    int hq = nq >> 10, wq = (nq >> 5) & 31, dq = nq & 31;
    size_t pos = (size_t)((bq * PD + hq + 1) * PD + (wq + 1)) * PD + (dq + 1);
    f16* dst0 = h1p + pos * CHH;
#pragma unroll
    for (int ni = 0; ni < 4; ++ni) {
      int col = col0 + wc * 64 + ni * 16 + rl;
      float bias = fc1b[col];
#pragma unroll
      for (int r = 0; r < 4; ++r)
        dst0[(size_t)r * CHH + col] = (f16)(acc[mi][ni][r] + bias);
    }
  }
}

// ---- depthwise 3x3x3 conv + bias + GELU (v5: padded input, branch-free) ----
// block = 256 = 4 waves; wave = one (b,h,w) line: 8 c8 x 8 dq (4 d-outputs each).
// grid = (BN/32/4, 10 ch-groups). All 54 tap loads unconditional, const offsets.
__global__ __launch_bounds__(256) void k_conv(const f16* __restrict__ h1p,
                                              const f16* __restrict__ wTh,
                                              const float* __restrict__ dwb,
                                              bf16* __restrict__ h2b) {
  __shared__ f16 lw[27 * 64];   // [tap][64ch]
  __shared__ float lb[64];
  const int tid = threadIdx.x;
  const int cg = blockIdx.y;     // 0..9
#pragma unroll
  for (int i = 0; i < 7; ++i) {
    int idx = i * 256 + tid;
    if (idx < 27 * 64) lw[idx] = wTh[(idx >> 6) * CHH + cg * 64 + (idx & 63)];
  }
  if (tid < 64) lb[tid] = dwb[cg * 64 + tid];
  __syncthreads();

  const int lane = tid & 63, wave = tid >> 6;
  const int line = blockIdx.x * 4 + wave;   // b*1024 + h*32 + w
  const int c8 = lane & 7, dq = lane >> 3;
  const int d0 = dq * 4;
  const int ch0 = cg * 64 + c8 * 8;
  const int w = line & 31, h = (line >> 5) & 31, b = line >> 10;

  // corner of the 3x3x6 input window in padded coords: (b, h+0, w+0, d0+0)
  const size_t cidx = (size_t)((b * PD + h) * PD + w) * PD + d0;
  const f16* base = h1p + cidx * CHH + ch0;

  f16x8 acc[4];
  {
    f16x8 binit;
#pragma unroll
    for (int j = 0; j < 8; ++j) binit[j] = (f16)lb[c8 * 8 + j];
    acc[0] = binit; acc[1] = binit; acc[2] = binit; acc[3] = binit;
  }

#pragma unroll
  for (int kz = 0; kz < 3; ++kz) {
#pragma unroll
    for (int ky = 0; ky < 3; ++ky) {
      const f16* pb = base + (size_t)(kz * PD + ky) * PD * CHH;
      f16x8 wt[3];
#pragma unroll
      for (int kx = 0; kx < 3; ++kx)
        wt[kx] = *(const f16x8*)&lw[((kz * 9 + ky * 3 + kx) << 6) + c8 * 8];
      f16x8 v[6];
#pragma unroll
      for (int j = 0; j < 6; ++j)
        v[j] = *(const f16x8*)(pb + (size_t)j * CHH);
#pragma unroll
      for (int o = 0; o < 4; ++o)
#pragma unroll
        for (int kx = 0; kx < 3; ++kx)
          acc[o] = v[o + kx] * wt[kx] + acc[o];   // v_pk_fma_f16
    }
  }

  const ptrdiff_t obase = (ptrdiff_t)(line * 32 + d0) * CHH + ch0;
#pragma unroll
  for (int o = 0; o < 4; ++o) {
    bf16x8 ovec;
#pragma unroll
    for (int j = 0; j < 8; ++j) {
      float xv = (float)acc[o][j];
      // gelu(x) = x - x / (1 + exp2(x*(C1 + C2*x^2)))  [tanh form, div-free]
      float x2 = xv * xv;
      float u = xv * (2.3022078f + 0.102943324f * x2);
      float e = __builtin_exp2f(u);
      float r = __builtin_amdgcn_rcpf(1.0f + e);
      ovec[j] = (bf16)(xv - xv * r);
    }
    *(bf16x8*)&h2b[obase + (ptrdiff_t)o * CHH] = ovec;
  }
}

// ---- GEMM2: out[t,o] = sum_ch hs[t,ch] * fc2_w[o,ch] + fc2_b[o], shift(W) fused ----
// tile 128(M) x 160(N full), BK=64, K=640 (10 steps). 4 waves, each 32x160 (2x10 frags).
__global__ __launch_bounds__(256) void k_gemm2(const bf16* __restrict__ h2b,
                                               const bf16* __restrict__ w2b,
                                               const float* __restrict__ fc2b,
                                               const bf16* __restrict__ zp,
                                               float* __restrict__ out) {
  __shared__ bf16 lsA[128 * 64];  // 16KB
  __shared__ bf16 lsB[160 * 64];  // 20KB
  const int tid = threadIdx.x, lane = tid & 63, wave = tid >> 6;
  const int row0 = blockIdx.x * 128;
  const int rl = lane & 15, kb = (lane >> 4) * 8;

  f32x4 acc[2][10] = {};

  for (int kt = 0; kt < 10; ++kt) {
    __syncthreads();
    const int k0 = kt * 64;
    const int s = (k0 >> 7) - 2;  // shift for 128-channel chunk; uniform per 64-K slice
#pragma unroll
    for (int issue = 0; issue < 4; ++issue) {
      int c = issue * 256 + tid;
      int ar = c >> 3;
      int kc = (c & 7) * 8;
      int t = row0 + ar;
      int w = (t >> 5) & 31;
      int wsv = w - s;
      const bf16* src;
      if (wsv >= 0 && wsv < 32)
        src = h2b + (size_t)(t - s * 32) * CHH + k0 + kc;
      else
        src = zp + (size_t)(c & 63) * 8;
      async16(src, (char*)lsA + issue * 4096 + wave * 1024);
    }
#pragma unroll
    for (int issue = 0; issue < 5; ++issue) {
      int c = issue * 256 + tid;
      int br = c >> 3;
      int kc = (c & 7) * 8;
      const bf16* src = w2b + (size_t)br * CHH + k0 + kc;
      async16(src, (char*)lsB + issue * 4096 + wave * 1024);
    }
    __syncthreads();
#pragma unroll
    for (int kk = 0; kk < 2; ++kk) {
      bf16x8 af[2], bfr[10];
#pragma unroll
      for (int mi = 0; mi < 2; ++mi)
        af[mi] = *(const bf16x8*)&lsA[(wave * 32 + mi * 16 + rl) * 64 + kk * 32 + kb];
#pragma unroll
      for (int ni = 0; ni < 10; ++ni)
        bfr[ni] = *(const bf16x8*)&lsB[(ni * 16 + rl) * 64 + kk * 32 + kb];
#pragma unroll
      for (int mi = 0; mi < 2; ++mi)
#pragma unroll
        for (int ni = 0; ni < 10; ++ni)
          acc[mi][ni] = __builtin_amdgcn_mfma_f32_16x16x32_bf16(af[mi], bfr[ni], acc[mi][ni], 0, 0, 0);
    }
  }
  const int rq = lane >> 4;
#pragma unroll
  for (int mi = 0; mi < 2; ++mi) {
#pragma unroll
    for (int ni = 0; ni < 10; ++ni) {
      int col = ni * 16 + rl;
      float bias = fc2b[col];
#pragma unroll
      for (int r = 0; r < 4; ++r) {
        int row = row0 + wave * 32 + mi * 16 + rq * 4 + r;
        out[(size_t)row * CIN + col] = acc[mi][ni][r] + bias;
      }
    }
  }
}

extern "C" void kernel_launch(void* const* d_in, const int* in_sizes, int n_in,
                              void* d_out, int out_size, void* d_ws, size_t ws_size,
                              hipStream_t stream) {
  const float* x    = (const float*)d_in[0];
  const float* fc1w = (const float*)d_in[1];
  const float* fc1b = (const float*)d_in[2];
  const float* dww  = (const float*)d_in[3];
  const float* dwb  = (const float*)d_in[4];
  const float* fc2w = (const float*)d_in[5];
  const float* fc2b = (const float*)d_in[6];

  char* ws = (char*)d_ws;
  bf16* w1b  = (bf16*)(ws + W1_OFF);
  bf16* w2b  = (bf16*)(ws + W2_OFF);
  f16*  wTh  = (f16*)(ws + WTH_OFF);
  bf16* zp   = (bf16*)(ws + ZP_OFF);
  bf16* xb   = (bf16*)(ws + U_OFF);     // alive: prep_x .. gemm1
  bf16* h2b  = (bf16*)(ws + U_OFF);     // alive: conv .. gemm2 (aliases xb)
  f16*  h1p  = (f16*)(ws + H1P_OFF);
  float* out = (float*)d_out;

  k_zero_pad<<<(2 * PT * 80) / 256, 256, 0, stream>>>(h1p);
  k_prep_x<<<(BN * CIN / 4) / 256, 256, 0, stream>>>(x, xb, BN * CIN / 4);
  k_prep_w<<<943, 256, 0, stream>>>(fc1w, fc2w, dww, w1b, w2b, wTh, (unsigned*)zp);
  dim3 g1(512, 5);
  k_gemm1<<<g1, 256, 0, stream>>>(xb, w1b, fc1b, zp, h1p);
  dim3 gc(BN / 32 / 4, 10);
  k_conv<<<gc, 256, 0, stream>>>(h1p, wTh, dwb, h2b);
  k_gemm2<<<512, 256, 0, stream>>>(h2b, w2b, fc2b, zp, out);
}